// Round 1
// baseline (175.048 us; speedup 1.0000x reference)
//
#include <hip/hip_runtime.h>

#define N_ATOMS 512
#define N_MOL   16
#define HIDDEN  128
#define FILTERS 128
#define NUM_RBF 50
#define CUTOFF  10.0f
#define N_LAYERS 3

#define KBINS  1024          // lerp bins over [0, CUTOFF]
#define TROWS  (KBINS + 2)   // conceptual plain rows: 0..1023 real, 1024 = phi(10)=0, 1025 = 0 pad
#define PROWS  (KBINS + 1)   // pair rows 0..1024; row k = {phi_k, phi_{k+1}}
#define JT     8             // j-tile per block in aggregation
#define ICH    64            // i-chunk per block
#define NCHUNK (N_ATOMS / ICH)

// ---------------- distance -> (bin, frac) precompute ----------------
__global__ void k_dist(const float* __restrict__ pos, float2* __restrict__ kw) {
    int i = blockIdx.x * 256 + threadIdx.x;   // grid (2, 512)
    int j = blockIdx.y;
    float dx = pos[i*3+0] - pos[j*3+0];
    float dy = pos[i*3+1] - pos[j*3+1];
    float dz = pos[i*3+2] - pos[j*3+2];
    float d  = sqrtf(dx*dx + dy*dy + dz*dz);
    int   k;
    float w;
    if (i == j || d >= CUTOFF) { k = KBINS; w = 0.f; }   // points at all-zero pair row
    else {
        float t = d * ((float)KBINS / CUTOFF);
        k = (int)t;
        if (k > KBINS - 1) k = KBINS - 1;
        w = t - (float)k;
    }
    kw[(size_t)j * N_ATOMS + i] = make_float2(w, __int_as_float(k));
}

// ---------------- per-layer filter table build ----------------
#define BPB 16
__global__ void __launch_bounds__(128) k_table(const float* __restrict__ fw1,
        const float* __restrict__ fb1, const float* __restrict__ fw2,
        const float* __restrict__ fb2, float2* __restrict__ tabp) {
    int l    = blockIdx.y;
    int bin0 = blockIdx.x * BPB;
    __shared__ float s_w1[NUM_RBF * FILTERS];
    __shared__ float s_w2[FILTERS * FILTERS];
    __shared__ float s_rbf[2][NUM_RBF];
    __shared__ float s_h[2][FILTERS];
    int t = threadIdx.x;
    for (int idx = t; idx < NUM_RBF * FILTERS; idx += 128) s_w1[idx] = fw1[l*NUM_RBF*FILTERS + idx];
    for (int idx = t; idx < FILTERS * FILTERS; idx += 128) s_w2[idx] = fw2[l*FILTERS*FILTERS + idx];
    float bv1 = fb1[l*FILTERS + t];
    float bv2 = fb2[l*FILTERS + t];
    for (int b = 0; b < BPB; b += 2) {
        int binA = bin0 + b, binB = bin0 + b + 1;
        float dA = binA * (CUTOFF / (float)KBINS);
        float dB = binB * (CUTOFF / (float)KBINS);
        __syncthreads();
        if (t < NUM_RBF) {
            float cr = t * (CUTOFF / (float)(NUM_RBF - 1));
            float xa = dA - cr, xb = dB - cr;
            s_rbf[0][t] = expf(-xa*xa * 12.5f);   // 1/(2*width^2), width = 0.2
            s_rbf[1][t] = expf(-xb*xb * 12.5f);
        }
        __syncthreads();
        float aA = bv1, aB = bv1;
        for (int r = 0; r < NUM_RBF; r++) {
            float w = s_w1[r*FILTERS + t];
            aA = fmaf(s_rbf[0][r], w, aA);
            aB = fmaf(s_rbf[1][r], w, aB);
        }
        s_h[0][t] = aA / (1.f + expf(-aA));       // silu
        s_h[1][t] = aB / (1.f + expf(-aB));
        __syncthreads();
        float oA = bv2, oB = bv2;
        #pragma unroll 4
        for (int hh = 0; hh < FILTERS; hh++) {
            float w = s_w2[hh*FILTERS + t];
            oA = fmaf(s_h[0][hh], w, oA);
            oB = fmaf(s_h[1][hh], w, oB);
        }
        float envA = (binA >= KBINS) ? 0.f : 0.5f*(cosf(dA * (3.14159265358979f/CUTOFF)) + 1.f);
        float envB = (binB >= KBINS) ? 0.f : 0.5f*(cosf(dB * (3.14159265358979f/CUTOFF)) + 1.f);
        float pA = oA * envA, pB = oB * envB;
        // scatter value of bin into pair rows: row k = {phi_k, phi_{k+1}}
        size_t base = (size_t)l * PROWS * FILTERS;
        if (binA <= KBINS)                tabp[base + (size_t)binA*FILTERS + t].x     = pA;
        if (binA >= 1 && binA <= KBINS+1) tabp[base + (size_t)(binA-1)*FILTERS + t].y = pA;
        if (binB <= KBINS)                tabp[base + (size_t)binB*FILTERS + t].x     = pB;
        if (binB <= KBINS+1)              tabp[base + (size_t)(binB-1)*FILTERS + t].y = pB;
    }
}

// ---------------- embedding gather + first xj = x @ d1w[0] + d1b[0] ----------------
__global__ void __launch_bounds__(256) k_pre(const int* __restrict__ an,
        const float* __restrict__ emb, const float* __restrict__ w1,
        const float* __restrict__ b1, float* __restrict__ x, float* __restrict__ xj) {
    __shared__ float s_w[HIDDEN * FILTERS];
    __shared__ float s_row[2][HIDDEN];
    int t = threadIdx.x, c = t & 127, sub = t >> 7;
    for (int idx = t; idx < HIDDEN * FILTERS; idx += 256) s_w[idx] = w1[idx];
    float bv = b1[c];
    int r0 = blockIdx.x * 4;
    for (int rr = 0; rr < 2; rr++) {
        int i = r0 + rr*2 + sub;
        float xv = emb[an[i]*HIDDEN + c];
        x[i*HIDDEN + c] = xv;
        __syncthreads();
        s_row[sub][c] = xv;
        __syncthreads();
        float acc = bv;
        #pragma unroll 8
        for (int h = 0; h < HIDDEN; h++) acc = fmaf(s_row[sub][h], s_w[h*FILTERS + c], acc);
        xj[i*FILTERS + c] = acc;
    }
}

// ---------------- main aggregation: agg[j,f] = sum_i xj[i,f] * lerp(tab, d_ij)[f] ----------------
__global__ void __launch_bounds__(256) k_agg(const float2* __restrict__ kw,
        const float* __restrict__ xj, const float2* __restrict__ tabp,
        float* __restrict__ partial) {
    int t = threadIdx.x;
    int f = t & 127, jsub = t >> 7;
    int j0 = blockIdx.x * JT;
    int i0 = blockIdx.y * ICH;
    __shared__ float2 s_kw[JT][ICH];
    for (int idx = t; idx < JT * ICH; idx += 256) {
        int jj = idx / ICH, ii = idx % ICH;
        s_kw[jj][ii] = kw[(size_t)(j0 + jj) * N_ATOMS + i0 + ii];
    }
    __syncthreads();
    float acc[JT/2];
    #pragma unroll
    for (int a = 0; a < JT/2; a++) acc[a] = 0.f;
    for (int ii = 0; ii < ICH; ii++) {
        float xv = xj[(i0 + ii)*FILTERS + f];
        #pragma unroll
        for (int a = 0; a < JT/2; a++) {
            int jj = a*2 + jsub;
            float2 kwv = s_kw[jj][ii];
            int   k = __float_as_int(kwv.y);
            float2 p = tabp[(size_t)k * FILTERS + f];
            acc[a] = fmaf(xv, fmaf(kwv.x, p.y - p.x, p.x), acc[a]);
        }
    }
    #pragma unroll
    for (int a = 0; a < JT/2; a++) {
        int jj = a*2 + jsub;
        partial[((size_t)blockIdx.y * N_ATOMS + j0 + jj)*FILTERS + f] = acc[a];
    }
}

// ---------------- x += (sum partials) @ d2w + d2b;  optionally xj = x @ d1w[l+1] + d1b[l+1] ----------------
template<int LAST>
__global__ void __launch_bounds__(256) k_upd(float* __restrict__ x,
        const float* __restrict__ partial, const float* __restrict__ w2,
        const float* __restrict__ b2, const float* __restrict__ w1n,
        const float* __restrict__ b1n, float* __restrict__ xj) {
    __shared__ float s_w2[FILTERS * HIDDEN];
    __shared__ float s_w1[LAST ? 1 : HIDDEN * FILTERS];
    __shared__ float s_agg[2][FILTERS];
    __shared__ float s_xn[2][HIDDEN];
    int t = threadIdx.x, c = t & 127, sub = t >> 7;
    for (int idx = t; idx < FILTERS * HIDDEN; idx += 256) s_w2[idx] = w2[idx];
    if (!LAST) for (int idx = t; idx < HIDDEN * FILTERS; idx += 256) s_w1[idx] = w1n[idx];
    float b2v = b2[c];
    int r0 = blockIdx.x * 4;
    for (int rr = 0; rr < 2; rr++) {
        int j = r0 + rr*2 + sub;
        float a = 0.f;
        #pragma unroll
        for (int cc = 0; cc < NCHUNK; cc++) a += partial[((size_t)cc * N_ATOMS + j)*FILTERS + c];
        __syncthreads();
        s_agg[sub][c] = a;
        __syncthreads();
        float acc = x[j*HIDDEN + c] + b2v;
        #pragma unroll 8
        for (int ff = 0; ff < FILTERS; ff++) acc = fmaf(s_agg[sub][ff], s_w2[ff*HIDDEN + c], acc);
        x[j*HIDDEN + c] = acc;
        if (!LAST) {
            s_xn[sub][c] = acc;
            __syncthreads();
            float a2 = b1n[c];
            #pragma unroll 8
            for (int hh = 0; hh < HIDDEN; hh++) a2 = fmaf(s_xn[sub][hh], s_w1[hh*FILTERS + c], a2);
            xj[j*FILTERS + c] = a2;
        }
        __syncthreads();
    }
}

// ---------------- molecule pool + output MLP ----------------
__global__ void __launch_bounds__(128) k_pool(const float* __restrict__ x,
        const int* __restrict__ batch, const float* __restrict__ ow1,
        const float* __restrict__ ob1, const float* __restrict__ ow2,
        const float* __restrict__ ob2, float* __restrict__ out) {
    int m = blockIdx.x, t = threadIdx.x;
    float s = 0.f; int cnt = 0;
    for (int i = 0; i < N_ATOMS; i++) {
        if (batch[i] == m) { s += x[i*HIDDEN + t]; cnt++; }
    }
    float mol = s / (float)(cnt > 0 ? cnt : 1);
    __shared__ float s_mol[HIDDEN];
    __shared__ float s_h[HIDDEN/2];
    s_mol[t] = mol;
    __syncthreads();
    if (t < HIDDEN/2) {
        float a = ob1[t];
        for (int h = 0; h < HIDDEN; h++) a = fmaf(s_mol[h], ow1[h*(HIDDEN/2) + t], a);
        s_h[t] = a / (1.f + expf(-a));
    }
    __syncthreads();
    if (t == 0) {
        float a = ob2[0];
        for (int h = 0; h < HIDDEN/2; h++) a = fmaf(s_h[h], ow2[h], a);
        out[m] = a;
    }
}

extern "C" void kernel_launch(void* const* d_in, const int* in_sizes, int n_in,
                              void* d_out, int out_size, void* d_ws, size_t ws_size,
                              hipStream_t stream) {
    const int*   an    = (const int*)  d_in[0];
    const float* pos   = (const float*)d_in[1];
    const int*   batch = (const int*)  d_in[2];
    const float* emb   = (const float*)d_in[3];
    const float* fw1   = (const float*)d_in[4];
    const float* fb1   = (const float*)d_in[5];
    const float* fw2   = (const float*)d_in[6];
    const float* fb2   = (const float*)d_in[7];
    const float* d1w   = (const float*)d_in[8];
    const float* d1b   = (const float*)d_in[9];
    const float* d2w   = (const float*)d_in[10];
    const float* d2b   = (const float*)d_in[11];
    const float* ow1   = (const float*)d_in[12];
    const float* ob1   = (const float*)d_in[13];
    const float* ow2   = (const float*)d_in[14];
    const float* ob2   = (const float*)d_in[15];
    float* out = (float*)d_out;

    float*  ws   = (float*)d_ws;
    float*  x    = ws;                               // 512*128          = 65536 f
    float*  xj   = x + N_ATOMS*HIDDEN;               // 65536 f
    float2* kw   = (float2*)(xj + N_ATOMS*FILTERS);  // 512*512 float2   = 2 MB
    float2* tabp = kw + (size_t)N_ATOMS*N_ATOMS;     // 3*1025*128 f2    = 3.15 MB
    float*  part = (float*)(tabp + (size_t)N_LAYERS*PROWS*FILTERS); // 8*512*128 = 2 MB

    k_dist <<<dim3(2, N_ATOMS), 256, 0, stream>>>(pos, kw);
    k_table<<<dim3((TROWS + BPB - 1)/BPB, N_LAYERS), 128, 0, stream>>>(fw1, fb1, fw2, fb2, tabp);
    k_pre  <<<N_ATOMS/4, 256, 0, stream>>>(an, emb, d1w, d1b, x, xj);

    for (int l = 0; l < N_LAYERS; l++) {
        k_agg<<<dim3(N_ATOMS/JT, NCHUNK), 256, 0, stream>>>(
            kw, xj, tabp + (size_t)l * PROWS * FILTERS, part);
        if (l < N_LAYERS - 1) {
            k_upd<0><<<N_ATOMS/4, 256, 0, stream>>>(x, part,
                d2w + (size_t)l*FILTERS*HIDDEN, d2b + (size_t)l*HIDDEN,
                d1w + (size_t)(l+1)*HIDDEN*FILTERS, d1b + (size_t)(l+1)*FILTERS, xj);
        } else {
            k_upd<1><<<N_ATOMS/4, 256, 0, stream>>>(x, part,
                d2w + (size_t)l*FILTERS*HIDDEN, d2b + (size_t)l*HIDDEN,
                d1w, d1b, xj);
        }
    }
    k_pool<<<N_MOL, 128, 0, stream>>>(x, batch, ow1, ob1, ow2, ob2, out);
}

// Round 2
// 140.942 us; speedup vs baseline: 1.2420x; 1.2420x over previous
//
#include <hip/hip_runtime.h>
#include <math.h>

#define N_ATOMS 512
#define N_MOL   16
#define HIDDEN  128
#define FILTERS 128
#define NUM_RBF 50
#define CUTOFF  10.0f
#define N_LAYERS 3

#define KBINS  1024          // lerp bins over [0, CUTOFF]
#define TROWS  (KBINS + 2)   // bins evaluated: 0..1025 (1024,1025 are zero rows)
#define PROWS  (KBINS + 1)   // pair rows 0..1024; row k = {phi_k, phi_{k+1}} as 2x bf16

__device__ __forceinline__ unsigned short f2bf(float v) {
    unsigned u = __float_as_uint(v);
    u += 0x7fffu + ((u >> 16) & 1u);          // round-to-nearest-even
    return (unsigned short)(u >> 16);
}

// ---------------- fused: all-pairs dist->(bin,frac)  +  embedding + xj0 ----------------
// blocks 0..1023  : distance table kw[j][i]
// blocks 1024..1151: x = emb[an], xjA = x @ d1w[0] + d1b[0]   (4 atom rows per block)
__global__ void __launch_bounds__(256) k_prep(const float* __restrict__ pos,
        const int* __restrict__ an, const float* __restrict__ emb,
        const float* __restrict__ w1, const float* __restrict__ b1,
        float2* __restrict__ kw, float* __restrict__ x, float* __restrict__ xj) {
    int bid = blockIdx.x, t = threadIdx.x;
    if (bid < 1024) {
        int i = (bid & 1) * 256 + t;
        int j = bid >> 1;
        float dx = pos[i*3+0] - pos[j*3+0];
        float dy = pos[i*3+1] - pos[j*3+1];
        float dz = pos[i*3+2] - pos[j*3+2];
        float d  = sqrtf(dx*dx + dy*dy + dz*dz);
        int   k; float w;
        if (i == j || d >= CUTOFF) { k = KBINS; w = 0.f; }  // all-zero pair row
        else {
            float tt = d * ((float)KBINS / CUTOFF);
            k = (int)tt;
            if (k > KBINS - 1) k = KBINS - 1;
            w = tt - (float)k;
        }
        kw[(size_t)j * N_ATOMS + i] = make_float2(w, __int_as_float(k));
    } else {
        __shared__ float s_row[2][HIDDEN];
        int c = t & 127, sub = t >> 7;
        int r0 = (bid - 1024) * 4;
        float bv = b1[c];
        for (int rr = 0; rr < 2; rr++) {
            int i = r0 + rr*2 + sub;
            float xv = emb[an[i]*HIDDEN + c];
            x[i*HIDDEN + c] = xv;
            s_row[sub][c] = xv;
            __syncthreads();
            float acc = bv;
            #pragma unroll 8
            for (int h = 0; h < HIDDEN; h++) acc = fmaf(s_row[sub][h], w1[h*FILTERS + c], acc);
            xj[i*FILTERS + c] = acc;
            __syncthreads();
        }
    }
}

// ---------------- per-layer filter table (bf16 pair rows) ----------------
#define BPB 16
__global__ void __launch_bounds__(256) k_table(const float* __restrict__ fw1,
        const float* __restrict__ fb1, const float* __restrict__ fw2,
        const float* __restrict__ fb2, unsigned short* __restrict__ tab) {
    int l = blockIdx.y, bin0 = blockIdx.x * BPB;
    int t = threadIdx.x, c = t & 127, sub = t >> 7;
    __shared__ float s_w1[NUM_RBF * FILTERS];
    __shared__ float s_rbf[2][NUM_RBF];
    __shared__ float s_h[2][FILTERS];
    for (int idx = t; idx < NUM_RBF * FILTERS; idx += 256) s_w1[idx] = fw1[l*NUM_RBF*FILTERS + idx];
    float bv1 = fb1[l*FILTERS + c];
    float bv2 = fb2[l*FILTERS + c];
    const float* w2p = fw2 + (size_t)l*FILTERS*FILTERS;
    size_t base = (size_t)l * PROWS * FILTERS * 2;
    for (int b = 0; b < BPB; b += 2) {
        int bin = bin0 + b + sub;
        float dd = bin * (CUTOFF / (float)KBINS);
        __syncthreads();
        if (c < NUM_RBF) {
            float cr = c * (CUTOFF / (float)(NUM_RBF - 1));
            float xx = dd - cr;
            s_rbf[sub][c] = expf(-xx*xx * 12.5f);    // 1/(2*w^2), w = 0.2
        }
        __syncthreads();
        float a = bv1;
        for (int r = 0; r < NUM_RBF; r++) a = fmaf(s_rbf[sub][r], s_w1[r*FILTERS + c], a);
        s_h[sub][c] = a / (1.f + expf(-a));           // silu
        __syncthreads();
        float o = bv2;
        #pragma unroll 4
        for (int hh = 0; hh < FILTERS; hh++) o = fmaf(s_h[sub][hh], w2p[hh*FILTERS + c], o);
        float env = (bin >= KBINS) ? 0.f : 0.5f*(cosf(dd * (3.14159265358979f/CUTOFF)) + 1.f);
        unsigned short pb = f2bf(o * env);
        if (bin <= KBINS)                tab[base + ((size_t)bin*FILTERS + c)*2 + 0] = pb;
        if (bin >= 1 && bin <= KBINS+1)  tab[base + ((size_t)(bin-1)*FILTERS + c)*2 + 1] = pb;
    }
}

// ---------------- fused layer: agg over all i + x update + next xj, one j-row per block ----
template<int LAST>
__global__ void __launch_bounds__(256) k_layer(const float2* __restrict__ kw,
        const unsigned int* __restrict__ tab, const float* __restrict__ xj_in,
        float* __restrict__ x, const float* __restrict__ w2, const float* __restrict__ b2,
        const float* __restrict__ w1n, const float* __restrict__ b1n,
        float* __restrict__ xj_out) {
    int j = blockIdx.x;
    int t = threadIdx.x, f = t & 127, half = t >> 7;
    __shared__ float2 s_kw[N_ATOMS];
    __shared__ float  s_red[2][FILTERS];
    __shared__ float  s_agg[FILTERS];
    __shared__ float  s_xn[HIDDEN];
    for (int idx = t; idx < N_ATOMS; idx += 256) s_kw[idx] = kw[(size_t)j * N_ATOMS + idx];
    __syncthreads();
    // ---- aggregation: each half sums 256 of the 512 source atoms ----
    float acc = 0.f;
    int i0 = half * 256;
    #pragma unroll 4
    for (int ii = 0; ii < 256; ii++) {
        float2 kwv = s_kw[i0 + ii];
        int k = __float_as_int(kwv.y);
        unsigned int pk = tab[(size_t)k * FILTERS + f];
        float lo = __uint_as_float(pk << 16);
        float hi = __uint_as_float(pk & 0xffff0000u);
        float phi = fmaf(kwv.x, hi - lo, lo);
        acc = fmaf(xj_in[(size_t)(i0 + ii)*FILTERS + f], phi, acc);
    }
    s_red[half][f] = acc;
    __syncthreads();
    if (half == 0) s_agg[f] = s_red[0][f] + s_red[1][f];
    __syncthreads();
    // ---- x update: v[c] = x[j,c] + b2[c] + sum_ff agg[ff] * w2[ff,c]; split ff over halves
    float v = 0.f;
    int ff0 = half * 64;
    #pragma unroll 8
    for (int ff = ff0; ff < ff0 + 64; ff++) v = fmaf(s_agg[ff], w2[ff*HIDDEN + f], v);
    s_red[half][f] = v;
    __syncthreads();
    if (half == 0) {
        float xnew = x[j*HIDDEN + f] + b2[f] + s_red[0][f] + s_red[1][f];
        x[j*HIDDEN + f] = xnew;
        s_xn[f] = xnew;
    }
    __syncthreads();
    if (!LAST) {
        float a2 = 0.f;
        int h0 = half * 64;
        #pragma unroll 8
        for (int hh = h0; hh < h0 + 64; hh++) a2 = fmaf(s_xn[hh], w1n[hh*FILTERS + f], a2);
        s_red[half][f] = a2;
        __syncthreads();
        if (half == 0) xj_out[j*FILTERS + f] = b1n[f] + s_red[0][f] + s_red[1][f];
    }
}

// ---------------- molecule pool + output MLP (binary search on sorted batch) ------------
__device__ __forceinline__ int lbound(const int* __restrict__ b, int n, int v) {
    int lo = 0, hi = n;
    while (lo < hi) { int mid = (lo + hi) >> 1; if (b[mid] < v) lo = mid + 1; else hi = mid; }
    return lo;
}

__global__ void __launch_bounds__(128) k_pool(const float* __restrict__ x,
        const int* __restrict__ batch, const float* __restrict__ ow1,
        const float* __restrict__ ob1, const float* __restrict__ ow2,
        const float* __restrict__ ob2, float* __restrict__ out) {
    int m = blockIdx.x, t = threadIdx.x;
    int lo = lbound(batch, N_ATOMS, m);
    int hi = lbound(batch, N_ATOMS, m + 1);
    float s = 0.f;
    for (int i = lo; i < hi; i++) s += x[i*HIDDEN + t];
    int cnt = hi - lo;
    float mol = s / (float)(cnt > 0 ? cnt : 1);
    __shared__ float s_mol[HIDDEN];
    __shared__ float s_h[HIDDEN/2];
    s_mol[t] = mol;
    __syncthreads();
    if (t < HIDDEN/2) {
        float a = ob1[t];
        for (int h = 0; h < HIDDEN; h++) a = fmaf(s_mol[h], ow1[h*(HIDDEN/2) + t], a);
        s_h[t] = a / (1.f + expf(-a));
    }
    __syncthreads();
    if (t == 0) {
        float a = ob2[0];
        for (int h = 0; h < HIDDEN/2; h++) a = fmaf(s_h[h], ow2[h], a);
        out[m] = a;
    }
}

extern "C" void kernel_launch(void* const* d_in, const int* in_sizes, int n_in,
                              void* d_out, int out_size, void* d_ws, size_t ws_size,
                              hipStream_t stream) {
    const int*   an    = (const int*)  d_in[0];
    const float* pos   = (const float*)d_in[1];
    const int*   batch = (const int*)  d_in[2];
    const float* emb   = (const float*)d_in[3];
    const float* fw1   = (const float*)d_in[4];
    const float* fb1   = (const float*)d_in[5];
    const float* fw2   = (const float*)d_in[6];
    const float* fb2   = (const float*)d_in[7];
    const float* d1w   = (const float*)d_in[8];
    const float* d1b   = (const float*)d_in[9];
    const float* d2w   = (const float*)d_in[10];
    const float* d2b   = (const float*)d_in[11];
    const float* ow1   = (const float*)d_in[12];
    const float* ob1   = (const float*)d_in[13];
    const float* ow2   = (const float*)d_in[14];
    const float* ob2   = (const float*)d_in[15];
    float* out = (float*)d_out;

    float*          ws   = (float*)d_ws;
    float2*         kw   = (float2*)ws;                         // 512*512*8B   = 2 MB
    float*          x    = (float*)(kw + (size_t)N_ATOMS*N_ATOMS);  // 256 KB
    float*          xjA  = x   + N_ATOMS*HIDDEN;                // 256 KB
    float*          xjB  = xjA + N_ATOMS*FILTERS;               // 256 KB
    unsigned short* tab  = (unsigned short*)(xjB + N_ATOMS*FILTERS); // 3*1025*128*2*2B = 1.575 MB

    k_prep <<<1024 + N_ATOMS/4, 256, 0, stream>>>(pos, an, emb, d1w, d1b, kw, x, xjA);
    k_table<<<dim3((TROWS + BPB - 1)/BPB, N_LAYERS), 256, 0, stream>>>(fw1, fb1, fw2, fb2, tab);

    float* xjs[2] = { xjA, xjB };
    for (int l = 0; l < N_LAYERS; l++) {
        const unsigned int* tl = (const unsigned int*)(tab + (size_t)l * PROWS * FILTERS * 2);
        float* xin  = xjs[l & 1];
        float* xout = xjs[(l + 1) & 1];
        if (l < N_LAYERS - 1) {
            k_layer<0><<<N_ATOMS, 256, 0, stream>>>(kw, tl, xin, x,
                d2w + (size_t)l*FILTERS*HIDDEN, d2b + (size_t)l*HIDDEN,
                d1w + (size_t)(l+1)*HIDDEN*FILTERS, d1b + (size_t)(l+1)*FILTERS, xout);
        } else {
            k_layer<1><<<N_ATOMS, 256, 0, stream>>>(kw, tl, xin, x,
                d2w + (size_t)l*FILTERS*HIDDEN, d2b + (size_t)l*HIDDEN,
                d1w, d1b, xout);
        }
    }
    k_pool<<<N_MOL, 128, 0, stream>>>(x, batch, ow1, ob1, ow2, ob2, out);
}

// Round 3
// 81.039 us; speedup vs baseline: 2.1600x; 1.7392x over previous
//
#include <hip/hip_runtime.h>
#include <math.h>

#define N_ATOMS 512
#define N_MOL   16
#define HIDDEN  128
#define FILTERS 128
#define NUM_RBF 50
#define CUTOFF  10.0f
#define N_LAYERS 3

#define KBINS  1024          // lerp bins over [0, CUTOFF]
#define TROWS  (KBINS + 2)   // bins evaluated: 0..1025 (>=1024 are zero rows)
#define PROWS  (KBINS + 1)   // pair rows 0..1024; row k = {phi_k, phi_{k+1}} as 2x bf16
#define TB     32            // bins per table block
#define TBLK   ((TROWS + TB - 1) / TB)   // 33 table blocks per layer

__device__ __forceinline__ unsigned short f2bf(float v) {
    unsigned u = __float_as_uint(v);
    u += 0x7fffu + ((u >> 16) & 1u);          // round-to-nearest-even
    return (unsigned short)(u >> 16);
}

// ============ front kernel: dist table ∥ embedding+xj0 ∥ filter tables ============
// blocks [0,1024)            : kw[j][i] distance->(frac,bin)
// blocks [1024,1088)         : x = emb[an], xj0 = x @ d1w[0] + d1b[0]   (8 atoms/block)
// blocks [1088,1088+3*33)    : per-layer bf16 filter table
__global__ void __launch_bounds__(256) k_front(const float* __restrict__ pos,
        const int* __restrict__ an, const float* __restrict__ emb,
        const float* __restrict__ d1w, const float* __restrict__ d1b,
        const float* __restrict__ fw1, const float* __restrict__ fb1,
        const float* __restrict__ fw2, const float* __restrict__ fb2,
        float2* __restrict__ kw, float* __restrict__ x, float* __restrict__ xj,
        unsigned short* __restrict__ tab) {
    __shared__ float s_row[8][HIDDEN];          // emb role
    __shared__ float s_rbf[TB][NUM_RBF];        // table role
    __shared__ float s_h[TB][FILTERS];          // table role
    int bid = blockIdx.x, t = threadIdx.x;

    if (bid < 1024) {
        // ---------- all-pairs distances ----------
        int i = (bid & 1) * 256 + t;
        int j = bid >> 1;
        float dx = pos[i*3+0] - pos[j*3+0];
        float dy = pos[i*3+1] - pos[j*3+1];
        float dz = pos[i*3+2] - pos[j*3+2];
        float d  = sqrtf(dx*dx + dy*dy + dz*dz);
        int   k; float w;
        if (i == j || d >= CUTOFF) { k = KBINS; w = 0.f; }   // all-zero pair row
        else {
            float tt = d * ((float)KBINS / CUTOFF);
            k = (int)tt;
            if (k > KBINS - 1) k = KBINS - 1;
            w = tt - (float)k;
        }
        kw[(size_t)j * N_ATOMS + i] = make_float2(w, __int_as_float(k));
    } else if (bid < 1024 + 64) {
        // ---------- embedding gather + xj0 = x @ d1w[0] + d1b[0], 8 atoms ----------
        int i0 = (bid - 1024) * 8;
        for (int idx = t; idx < 8 * HIDDEN; idx += 256) {
            int a = idx >> 7, c2 = idx & 127;
            float v = emb[an[i0 + a]*HIDDEN + c2];
            s_row[a][c2] = v;
            x[(i0 + a)*HIDDEN + c2] = v;
        }
        __syncthreads();
        int c = t & 127, g = t >> 7;           // g in {0,1}: atoms g*4..g*4+3
        float acc[4];
        float bv = d1b[c];
        #pragma unroll
        for (int aa = 0; aa < 4; aa++) acc[aa] = bv;
        #pragma unroll 4
        for (int h = 0; h < HIDDEN; h++) {
            float w = d1w[h*FILTERS + c];
            #pragma unroll
            for (int aa = 0; aa < 4; aa++) acc[aa] = fmaf(s_row[g*4 + aa][h], w, acc[aa]);
        }
        #pragma unroll
        for (int aa = 0; aa < 4; aa++) xj[(i0 + g*4 + aa)*FILTERS + c] = acc[aa];
    } else {
        // ---------- filter table: 32 bins, 16 accumulators per thread ----------
        int tb = bid - 1088;
        int l  = tb / TBLK, bx = tb % TBLK;
        int bin0 = bx * TB;
        const float* w1g = fw1 + (size_t)l*NUM_RBF*FILTERS;
        const float* w2g = fw2 + (size_t)l*FILTERS*FILTERS;
        // rbf for the 32 bins
        for (int idx = t; idx < TB * NUM_RBF; idx += 256) {
            int lb = idx / NUM_RBF, r = idx % NUM_RBF;
            float dd = (bin0 + lb) * (CUTOFF / (float)KBINS);
            float cr = r * (CUTOFF / (float)(NUM_RBF - 1));
            float xx = dd - cr;
            s_rbf[lb][r] = expf(-xx*xx * 12.5f);     // 1/(2*w^2), w = 0.2
        }
        __syncthreads();
        int c = t & 127, sub = t >> 7;               // thread owns bins lb = 2*bb+sub
        float h[16];
        float bv1 = fb1[l*FILTERS + c];
        #pragma unroll
        for (int bb = 0; bb < 16; bb++) h[bb] = bv1;
        for (int r = 0; r < NUM_RBF; r++) {
            float w = w1g[r*FILTERS + c];
            #pragma unroll
            for (int bb = 0; bb < 16; bb++) h[bb] = fmaf(s_rbf[2*bb + sub][r], w, h[bb]);
        }
        #pragma unroll
        for (int bb = 0; bb < 16; bb++) {
            float a = h[bb];
            s_h[2*bb + sub][c] = a / (1.f + expf(-a));   // silu
        }
        __syncthreads();
        float o[16];
        float bv2 = fb2[l*FILTERS + c];
        #pragma unroll
        for (int bb = 0; bb < 16; bb++) o[bb] = bv2;
        #pragma unroll 2
        for (int hh = 0; hh < FILTERS; hh++) {
            float w = w2g[hh*FILTERS + c];
            #pragma unroll
            for (int bb = 0; bb < 16; bb++) o[bb] = fmaf(s_h[2*bb + sub][hh], w, o[bb]);
        }
        size_t base = (size_t)l * PROWS * FILTERS * 2;
        #pragma unroll
        for (int bb = 0; bb < 16; bb++) {
            int bin = bin0 + 2*bb + sub;
            float dd = bin * (CUTOFF / (float)KBINS);
            float env = (bin >= KBINS) ? 0.f : 0.5f*(cosf(dd * (3.14159265358979f/CUTOFF)) + 1.f);
            unsigned short pb = f2bf(o[bb] * env);
            if (bin <= KBINS)               tab[base + ((size_t)bin*FILTERS + c)*2 + 0] = pb;
            if (bin >= 1 && bin <= KBINS+1) tab[base + ((size_t)(bin-1)*FILTERS + c)*2 + 1] = pb;
        }
    }
}

// ======== fused layer: agg over all i + x update + next xj; one j-row per block ========
template<int LAST>
__global__ void __launch_bounds__(512) k_layer(const float2* __restrict__ kw,
        const unsigned int* __restrict__ tab, const float* __restrict__ xj_in,
        float* __restrict__ x, const float* __restrict__ w2, const float* __restrict__ b2,
        const float* __restrict__ w1n, const float* __restrict__ b1n,
        float* __restrict__ xj_out) {
    int j = blockIdx.x;
    int t = threadIdx.x, f = t & 127, q = t >> 7;    // q in 0..3: i-quarter
    __shared__ float2 s_kw[N_ATOMS];
    __shared__ float  s_red[4][FILTERS];
    __shared__ float  s_agg[FILTERS];
    __shared__ float  s_xn[HIDDEN];
    s_kw[t] = kw[(size_t)j * N_ATOMS + t];
    __syncthreads();
    // ---- aggregation: each quarter sums 128 source atoms, 2 accumulators ----
    float acc0 = 0.f, acc1 = 0.f;
    int i0 = q * 128;
    #pragma unroll 4
    for (int ii = 0; ii < 128; ii += 2) {
        float2 kv0 = s_kw[i0 + ii];
        float2 kv1 = s_kw[i0 + ii + 1];
        unsigned int p0 = tab[(size_t)__float_as_int(kv0.y) * FILTERS + f];
        unsigned int p1 = tab[(size_t)__float_as_int(kv1.y) * FILTERS + f];
        float xv0 = xj_in[(size_t)(i0 + ii)*FILTERS + f];
        float xv1 = xj_in[(size_t)(i0 + ii + 1)*FILTERS + f];
        float lo0 = __uint_as_float(p0 << 16), hi0 = __uint_as_float(p0 & 0xffff0000u);
        float lo1 = __uint_as_float(p1 << 16), hi1 = __uint_as_float(p1 & 0xffff0000u);
        acc0 = fmaf(xv0, fmaf(kv0.x, hi0 - lo0, lo0), acc0);
        acc1 = fmaf(xv1, fmaf(kv1.x, hi1 - lo1, lo1), acc1);
    }
    s_red[q][f] = acc0 + acc1;
    __syncthreads();
    if (q == 0) s_agg[f] = s_red[0][f] + s_red[1][f] + s_red[2][f] + s_red[3][f];
    __syncthreads();
    // ---- x update: split the 128-term dot over quarters (32 each) ----
    float v = 0.f;
    int ff0 = q * 32;
    #pragma unroll 8
    for (int ff = ff0; ff < ff0 + 32; ff++) v = fmaf(s_agg[ff], w2[ff*HIDDEN + f], v);
    s_red[q][f] = v;
    __syncthreads();
    if (q == 0) {
        float xnew = x[j*HIDDEN + f] + b2[f] + s_red[0][f] + s_red[1][f] + s_red[2][f] + s_red[3][f];
        x[j*HIDDEN + f] = xnew;
        s_xn[f] = xnew;
    }
    __syncthreads();
    if (!LAST) {
        float a2 = 0.f;
        int h0 = q * 32;
        #pragma unroll 8
        for (int hh = h0; hh < h0 + 32; hh++) a2 = fmaf(s_xn[hh], w1n[hh*FILTERS + f], a2);
        s_red[q][f] = a2;
        __syncthreads();
        if (q == 0) xj_out[j*FILTERS + f] = b1n[f] + s_red[0][f] + s_red[1][f] + s_red[2][f] + s_red[3][f];
    }
}

// ============ molecule pool + output MLP (binary search on sorted batch) ============
__device__ __forceinline__ int lbound(const int* __restrict__ b, int n, int v) {
    int lo = 0, hi = n;
    while (lo < hi) { int mid = (lo + hi) >> 1; if (b[mid] < v) lo = mid + 1; else hi = mid; }
    return lo;
}

__global__ void __launch_bounds__(128) k_pool(const float* __restrict__ x,
        const int* __restrict__ batch, const float* __restrict__ ow1,
        const float* __restrict__ ob1, const float* __restrict__ ow2,
        const float* __restrict__ ob2, float* __restrict__ out) {
    int m = blockIdx.x, t = threadIdx.x;
    int lo = lbound(batch, N_ATOMS, m);
    int hi = lbound(batch, N_ATOMS, m + 1);
    float s = 0.f;
    for (int i = lo; i < hi; i++) s += x[i*HIDDEN + t];
    int cnt = hi - lo;
    float mol = s / (float)(cnt > 0 ? cnt : 1);
    __shared__ float s_mol[HIDDEN];
    __shared__ float s_h[HIDDEN/2];
    s_mol[t] = mol;
    __syncthreads();
    if (t < HIDDEN/2) {
        float a = ob1[t];
        for (int h = 0; h < HIDDEN; h++) a = fmaf(s_mol[h], ow1[h*(HIDDEN/2) + t], a);
        s_h[t] = a / (1.f + expf(-a));
    }
    __syncthreads();
    if (t == 0) {
        float a = ob2[0];
        for (int h = 0; h < HIDDEN/2; h++) a = fmaf(s_h[h], ow2[h], a);
        out[m] = a;
    }
}

extern "C" void kernel_launch(void* const* d_in, const int* in_sizes, int n_in,
                              void* d_out, int out_size, void* d_ws, size_t ws_size,
                              hipStream_t stream) {
    const int*   an    = (const int*)  d_in[0];
    const float* pos   = (const float*)d_in[1];
    const int*   batch = (const int*)  d_in[2];
    const float* emb   = (const float*)d_in[3];
    const float* fw1   = (const float*)d_in[4];
    const float* fb1   = (const float*)d_in[5];
    const float* fw2   = (const float*)d_in[6];
    const float* fb2   = (const float*)d_in[7];
    const float* d1w   = (const float*)d_in[8];
    const float* d1b   = (const float*)d_in[9];
    const float* d2w   = (const float*)d_in[10];
    const float* d2b   = (const float*)d_in[11];
    const float* ow1   = (const float*)d_in[12];
    const float* ob1   = (const float*)d_in[13];
    const float* ow2   = (const float*)d_in[14];
    const float* ob2   = (const float*)d_in[15];
    float* out = (float*)d_out;

    float*          ws   = (float*)d_ws;
    float2*         kw   = (float2*)ws;                              // 2 MB
    float*          x    = (float*)(kw + (size_t)N_ATOMS*N_ATOMS);   // 256 KB
    float*          xjA  = x   + N_ATOMS*HIDDEN;                     // 256 KB
    float*          xjB  = xjA + N_ATOMS*FILTERS;                    // 256 KB
    unsigned short* tab  = (unsigned short*)(xjB + N_ATOMS*FILTERS); // 1.575 MB

    k_front<<<1024 + 64 + N_LAYERS*TBLK, 256, 0, stream>>>(
        pos, an, emb, d1w, d1b, fw1, fb1, fw2, fb2, kw, x, xjA, tab);

    float* xjs[2] = { xjA, xjB };
    for (int l = 0; l < N_LAYERS; l++) {
        const unsigned int* tl = (const unsigned int*)(tab + (size_t)l * PROWS * FILTERS * 2);
        float* xin  = xjs[l & 1];
        float* xout = xjs[(l + 1) & 1];
        if (l < N_LAYERS - 1) {
            k_layer<0><<<N_ATOMS, 512, 0, stream>>>(kw, tl, xin, x,
                d2w + (size_t)l*FILTERS*HIDDEN, d2b + (size_t)l*HIDDEN,
                d1w + (size_t)(l+1)*HIDDEN*FILTERS, d1b + (size_t)(l+1)*FILTERS, xout);
        } else {
            k_layer<1><<<N_ATOMS, 512, 0, stream>>>(kw, tl, xin, x,
                d2w + (size_t)l*FILTERS*HIDDEN, d2b + (size_t)l*HIDDEN,
                d1w, d1b, xout);
        }
    }
    k_pool<<<N_MOL, 128, 0, stream>>>(x, batch, ow1, ob1, ow2, ob2, out);
}